// Round 1
// baseline (1663.784 us; speedup 1.0000x reference)
//
#include <hip/hip_runtime.h>

// ---------------- constants ----------------
#define S_LEN 2048
#define DM    4096
#define DI    8192
#define PD    18560
#define CD    10240
#define NH    128
#define NP    64
#define NG    8
#define NS    128
#define NCH   16
#define CL    128
#define EPSF  1e-5f

typedef unsigned short u16;
typedef unsigned int   u32;
typedef __bf16 bf16_t;
typedef bf16_t bf16x8 __attribute__((ext_vector_type(8)));
typedef float  f32x4  __attribute__((ext_vector_type(4)));

__device__ __forceinline__ float bf2f(u16 u){ u32 x = ((u32)u) << 16; float f; __builtin_memcpy(&f, &x, 4); return f; }
__device__ __forceinline__ u16 f2bf(float f){ u32 x; __builtin_memcpy(&x, &f, 4); u32 r = x + 0x7fffu + ((x >> 16) & 1u); return (u16)(r >> 16); }
__device__ __forceinline__ float siluf(float v){ return v / (1.f + expf(-v)); }

__device__ __forceinline__ void async16(const void* g, void* l){
  __builtin_amdgcn_global_load_lds((const __attribute__((address_space(1))) void*)g,
                                   (__attribute__((address_space(3))) void*)l, 16, 0, 0);
}

// ---------------- 1. RMSNorm (fp32 in -> bf16 out) ----------------
__global__ __launch_bounds__(256) void k_rms(const float* __restrict__ x, const float* __restrict__ nw, u16* __restrict__ h){
  int row = blockIdx.x; int t = threadIdx.x;
  const float* xr = x + (size_t)row * DM;
  float4 v[4]; float ss = 0.f;
  #pragma unroll
  for (int i = 0; i < 4; i++){
    v[i] = ((const float4*)xr)[i * 256 + t];
    ss += v[i].x*v[i].x + v[i].y*v[i].y + v[i].z*v[i].z + v[i].w*v[i].w;
  }
  #pragma unroll
  for (int o = 32; o > 0; o >>= 1) ss += __shfl_down(ss, o);
  __shared__ float sred[4];
  if ((t & 63) == 0) sred[t >> 6] = ss;
  __syncthreads();
  float sc = rsqrtf((sred[0]+sred[1]+sred[2]+sred[3]) / (float)DM + EPSF);
  u16* hr = h + (size_t)row * DM;
  #pragma unroll
  for (int i = 0; i < 4; i++){
    int c4 = i * 256 + t;
    float4 w4 = ((const float4*)nw)[c4];
    ushort4 o;
    o.x = f2bf(v[i].x * sc * w4.x); o.y = f2bf(v[i].y * sc * w4.y);
    o.z = f2bf(v[i].z * sc * w4.z); o.w = f2bf(v[i].w * sc * w4.w);
    ((ushort4*)hr)[c4] = o;
  }
}

// ---------------- 2. fp32 -> bf16 convert ----------------
__global__ __launch_bounds__(256) void k_cvt(const float4* __restrict__ in, ushort4* __restrict__ outv, int n4){
  int i = blockIdx.x * 256 + threadIdx.x;
  if (i < n4){
    float4 v = in[i]; ushort4 o;
    o.x = f2bf(v.x); o.y = f2bf(v.y); o.z = f2bf(v.z); o.w = f2bf(v.w);
    outv[i] = o;
  }
}

// ---------------- 3. GEMM: C[M][N] = A[M][K] * B[N][K]^T (both bf16, fp32 acc) ----------------
// 128x128 tile, BK=64, 4 waves (each 64x64), global_load_lds staging with XOR swizzle.
// EPI=0: write bf16 C, optional fp32 sidecar of last NH columns (dt). EPI=1: fp32 C = resid + acc.
template<int EPI>
__global__ __launch_bounds__(256) void k_gemm_bt(const u16* __restrict__ A, const u16* __restrict__ B,
    void* __restrict__ Cout, const float* __restrict__ resid, float* __restrict__ dts,
    int M, int N, int K){
  __shared__ __align__(16) u16 lA[128 * 64];
  __shared__ __align__(16) u16 lB[128 * 64];
  int t = threadIdx.x, lane = t & 63, w = t >> 6;
  int wr = w >> 1, wc = w & 1;
  int m0 = blockIdx.y * 128, n0 = blockIdx.x * 128;
  f32x4 acc[4][4] = {};
  int nkt = K >> 6;
  for (int kt = 0; kt < nkt; kt++){
    #pragma unroll
    for (int r = 0; r < 4; r++){
      int chunk = r * 256 + t;
      int row = chunk >> 3, p = chunk & 7;
      int psw = p ^ (row & 7);
      const u16* sa = A + (size_t)(m0 + row) * K + kt * 64 + psw * 8;
      const u16* sb = B + (size_t)(n0 + row) * K + kt * 64 + psw * 8;
      u16* da = lA + (size_t)(r * 256 + w * 64) * 8;   // wave-uniform base
      u16* db = lB + (size_t)(r * 256 + w * 64) * 8;
      async16(sa, da);
      async16(sb, db);
    }
    __syncthreads();
    #pragma unroll
    for (int ks = 0; ks < 2; ks++){
      bf16x8 av[4], bv[4];
      #pragma unroll
      for (int mi = 0; mi < 4; mi++){
        int row = wr * 64 + mi * 16 + (lane & 15);
        int p = ks * 4 + (lane >> 4);
        av[mi] = *(const bf16x8*)(lA + row * 64 + ((p ^ (row & 7)) << 3));
      }
      #pragma unroll
      for (int nj = 0; nj < 4; nj++){
        int row = wc * 64 + nj * 16 + (lane & 15);
        int p = ks * 4 + (lane >> 4);
        bv[nj] = *(const bf16x8*)(lB + row * 64 + ((p ^ (row & 7)) << 3));
      }
      #pragma unroll
      for (int mi = 0; mi < 4; mi++)
        #pragma unroll
        for (int nj = 0; nj < 4; nj++)
          acc[mi][nj] = __builtin_amdgcn_mfma_f32_16x16x32_bf16(av[mi], bv[nj], acc[mi][nj], 0, 0, 0);
    }
    __syncthreads();
  }
  #pragma unroll
  for (int mi = 0; mi < 4; mi++)
  #pragma unroll
  for (int nj = 0; nj < 4; nj++)
  #pragma unroll
  for (int r = 0; r < 4; r++){
    int row = m0 + wr * 64 + mi * 16 + ((lane >> 4) << 2) + r;
    int col = n0 + wc * 64 + nj * 16 + (lane & 15);
    float v = acc[mi][nj][r];
    if (EPI == 0){
      ((u16*)Cout)[(size_t)row * N + col] = f2bf(v);
      if (dts && col >= PD - NH) dts[(size_t)row * NH + (col - (PD - NH))] = v;
    } else {
      size_t ix = (size_t)row * N + col;
      ((float*)Cout)[ix] = resid[ix] + v;
    }
  }
}

// ---------------- 4. dt = softplus(dt_raw + dt_bias) ----------------
__global__ __launch_bounds__(256) void k_dt(const float* __restrict__ dtraw, const float* __restrict__ dt_bias, float* __restrict__ dtsp){
  int i = blockIdx.x * 256 + threadIdx.x;     // s*128 + h
  int hh = i & (NH - 1);
  float v = dtraw[i] + dt_bias[hh];
  dtsp[i] = (v > 20.f) ? v : log1pf(expf(v));
}

// ---------------- 5. per-chunk cumsum of A*dt, and decay = exp(last - acs) ----------------
__global__ __launch_bounds__(128) void k_cumsum(const float* __restrict__ dtsp, const float* __restrict__ A_log,
                                                float* __restrict__ acs, float* __restrict__ dec){
  int c = blockIdx.x; int hh = threadIdx.x;
  float Ah = -expf(A_log[hh]);
  float a = 0.f;
  float* ac = acs + ((size_t)c * NH + hh) * CL;
  for (int l = 0; l < CL; l++){ a += Ah * dtsp[(size_t)(c * CL + l) * NH + hh]; ac[l] = a; }
  float last = a;
  float* dc = dec + ((size_t)c * NH + hh) * CL;
  for (int l = 0; l < CL; l++) dc[l] = expf(last - ac[l]);
}

// ---------------- 6. causal conv (K=4) + SiLU + split ----------------
__global__ __launch_bounds__(256) void k_conv(const u16* __restrict__ proj, const float* __restrict__ cw, const float* __restrict__ cb,
                                              u16* __restrict__ hid, u16* __restrict__ Bm, u16* __restrict__ Cm){
  size_t i = (size_t)blockIdx.x * 256 + threadIdx.x;   // s*CD + c
  int c = (int)(i % CD); int s = (int)(i / CD);
  float acc = cb[c];
  #pragma unroll
  for (int k = 0; k < 4; k++){
    int ss = s - 3 + k;
    if (ss >= 0) acc += bf2f(proj[(size_t)ss * PD + DI + c]) * cw[c * 4 + k];
  }
  float v = siluf(acc);
  if (c < DI) hid[(size_t)s * DI + c] = f2bf(v);
  else if (c < DI + 1024) Bm[(size_t)s * 1024 + (c - DI)] = f2bf(v);
  else Cm[(size_t)s * 1024 + (c - DI - 1024)] = f2bf(v);
}

// ---------------- 7. tiled transpose bf16 [S][C] -> [C][S]; FUSE: *dt and *decay variants ----------------
template<int FUSE>
__global__ __launch_bounds__(256) void k_transpose(const u16* __restrict__ X, u16* __restrict__ XT, u16* __restrict__ XT2,
                                                   const float* __restrict__ dtsp, const float* __restrict__ dec, int S, int C){
  __shared__ u16 tile[64][65];
  int ts = blockIdx.x * 64, tc = blockIdx.y * 64;
  int t = threadIdx.x;
  #pragma unroll
  for (int k = 0; k < 16; k++){
    int li = k * 256 + t;
    int r = li >> 6, col = li & 63;
    tile[r][col] = X[(size_t)(ts + r) * C + tc + col];
  }
  __syncthreads();
  #pragma unroll
  for (int k = 0; k < 16; k++){
    int li = k * 256 + t;
    int cc = li >> 6, ss = li & 63;
    u16 v = tile[ss][cc];
    size_t oidx = (size_t)(tc + cc) * S + ts + ss;
    if (FUSE){
      int s = ts + ss; int hh = (tc + cc) >> 6;
      float val = bf2f(v) * dtsp[(size_t)s * NH + hh];
      XT[oidx] = f2bf(val);
      int ch = s >> 7, l = s & 127;
      XT2[oidx] = f2bf(val * dec[((size_t)ch * NH + hh) * CL + l]);
    } else {
      XT[oidx] = v;
    }
  }
}

// ---------------- 8. Mh[c][h][i][j] = (C_i . B_j) * exp(acs_i - acs_j), i>=j ----------------
__global__ __launch_bounds__(256) void k_mh(const u16* __restrict__ Cm, const u16* __restrict__ Bm,
                                            const float* __restrict__ acs, u16* __restrict__ Mh){
  int c = blockIdx.x, g = blockIdx.y;
  int t = threadIdx.x, lane = t & 63, w = t >> 6, wr = w >> 1, wc = w & 1;
  f32x4 acc[4][4] = {};
  #pragma unroll
  for (int ks = 0; ks < 4; ks++){
    bf16x8 av[4], bv[4];
    #pragma unroll
    for (int mi = 0; mi < 4; mi++){
      int i_ = wr * 64 + mi * 16 + (lane & 15);
      av[mi] = *(const bf16x8*)(Cm + (size_t)(c * CL + i_) * 1024 + g * NS + ks * 32 + ((lane >> 4) << 3));
    }
    #pragma unroll
    for (int nj = 0; nj < 4; nj++){
      int j_ = wc * 64 + nj * 16 + (lane & 15);
      bv[nj] = *(const bf16x8*)(Bm + (size_t)(c * CL + j_) * 1024 + g * NS + ks * 32 + ((lane >> 4) << 3));
    }
    #pragma unroll
    for (int mi = 0; mi < 4; mi++)
      #pragma unroll
      for (int nj = 0; nj < 4; nj++)
        acc[mi][nj] = __builtin_amdgcn_mfma_f32_16x16x32_bf16(av[mi], bv[nj], acc[mi][nj], 0, 0, 0);
  }
  __shared__ float sa[CL];
  for (int h = g * 16; h < g * 16 + 16; h++){
    if (t < CL) sa[t] = acs[((size_t)c * NH + h) * CL + t];
    __syncthreads();
    #pragma unroll
    for (int mi = 0; mi < 4; mi++)
    #pragma unroll
    for (int nj = 0; nj < 4; nj++)
    #pragma unroll
    for (int r = 0; r < 4; r++){
      int i_ = wr * 64 + mi * 16 + ((lane >> 4) << 2) + r;
      int j_ = wc * 64 + nj * 16 + (lane & 15);
      float v = (i_ >= j_) ? acc[mi][nj][r] * expf(sa[i_] - sa[j_]) : 0.f;
      Mh[(((size_t)c * NH + h) * CL + i_) * CL + j_] = f2bf(v);
    }
    __syncthreads();
  }
}

// ---------------- 9. Y_diag[c][l][h][p] = Mh @ hid_dt ----------------
__global__ __launch_bounds__(256) void k_ydiag(const u16* __restrict__ Mh, const u16* __restrict__ hdtT, float* __restrict__ Y){
  int b = blockIdx.x; int c = b >> 7, h = b & 127;
  int t = threadIdx.x, lane = t & 63, w = t >> 6;
  const u16* Mp = Mh + (((size_t)c * NH + h) * CL) * CL;
  const u16* Hp = hdtT + (size_t)h * 64 * S_LEN + c * CL;
  f32x4 acc[2][4] = {};
  #pragma unroll
  for (int ks = 0; ks < 4; ks++){
    bf16x8 av[2], bv[4];
    #pragma unroll
    for (int mi = 0; mi < 2; mi++){
      int i_ = w * 32 + mi * 16 + (lane & 15);
      av[mi] = *(const bf16x8*)(Mp + (size_t)i_ * CL + ks * 32 + ((lane >> 4) << 3));
    }
    #pragma unroll
    for (int nj = 0; nj < 4; nj++){
      int p_ = nj * 16 + (lane & 15);
      bv[nj] = *(const bf16x8*)(Hp + (size_t)p_ * S_LEN + ks * 32 + ((lane >> 4) << 3));
    }
    #pragma unroll
    for (int mi = 0; mi < 2; mi++)
      #pragma unroll
      for (int nj = 0; nj < 4; nj++)
        acc[mi][nj] = __builtin_amdgcn_mfma_f32_16x16x32_bf16(av[mi], bv[nj], acc[mi][nj], 0, 0, 0);
  }
  #pragma unroll
  for (int mi = 0; mi < 2; mi++)
  #pragma unroll
  for (int nj = 0; nj < 4; nj++)
  #pragma unroll
  for (int r = 0; r < 4; r++){
    int i_ = w * 32 + mi * 16 + ((lane >> 4) << 2) + r;
    int p_ = nj * 16 + (lane & 15);
    Y[(size_t)(c * CL + i_) * DI + h * 64 + p_] = acc[mi][nj][r];
  }
}

// ---------------- 10. states[c][h][p][n] = sum_l hid_dt*decay (A) x B (B-op) ----------------
__global__ __launch_bounds__(256) void k_states(const u16* __restrict__ hddec, const u16* __restrict__ BmT, float* __restrict__ states){
  int b = blockIdx.x; int c = b >> 7, h = b & 127; int g = h >> 4;
  int t = threadIdx.x, lane = t & 63, w = t >> 6;
  f32x4 acc[8] = {};
  #pragma unroll
  for (int ks = 0; ks < 4; ks++){
    int p_ = w * 16 + (lane & 15);
    bf16x8 av = *(const bf16x8*)(hddec + (size_t)(h * 64 + p_) * S_LEN + c * CL + ks * 32 + ((lane >> 4) << 3));
    #pragma unroll
    for (int nj = 0; nj < 8; nj++){
      int n_ = nj * 16 + (lane & 15);
      bf16x8 bv = *(const bf16x8*)(BmT + (size_t)(g * NS + n_) * S_LEN + c * CL + ks * 32 + ((lane >> 4) << 3));
      acc[nj] = __builtin_amdgcn_mfma_f32_16x16x32_bf16(av, bv, acc[nj], 0, 0, 0);
    }
  }
  #pragma unroll
  for (int nj = 0; nj < 8; nj++)
  #pragma unroll
  for (int r = 0; r < 4; r++){
    int p_ = w * 16 + ((lane >> 4) << 2) + r;
    int n_ = nj * 16 + (lane & 15);
    states[(((size_t)c * NH + h) * NP + p_) * NS + n_] = acc[nj][r];
  }
}

// ---------------- 11. sequential inter-chunk scan ----------------
__global__ __launch_bounds__(256) void k_scan(const float* __restrict__ states, const float* __restrict__ acs, u16* __restrict__ prev){
  int i = blockIdx.x * 256 + threadIdx.x;       // h*8192 + p*128 + n
  int n_ = i & 127; int p_ = (i >> 7) & 63; int h = i >> 13;
  float Sv = 0.f;
  for (int c = 0; c < NCH; c++){
    size_t ix = (((size_t)c * NH + h) * NP + p_) * NS + n_;
    prev[ix] = f2bf(Sv);
    float dA = acs[((size_t)c * NH + h) * CL + CL - 1];
    Sv = Sv * expf(dA) + states[ix];
  }
}

// ---------------- 12. Y += Y_off + D*hid ----------------
__global__ __launch_bounds__(256) void k_yoff(const u16* __restrict__ Cm, const u16* __restrict__ prev,
    const float* __restrict__ acs, const float* __restrict__ Dp, const u16* __restrict__ hid, float* __restrict__ Y){
  int b = blockIdx.x; int c = b >> 7, h = b & 127; int g = h >> 4;
  int t = threadIdx.x, lane = t & 63, w = t >> 6;
  const u16* Pp = prev + (((size_t)c * NH + h) * NP) * NS;
  f32x4 acc[2][4] = {};
  #pragma unroll
  for (int ks = 0; ks < 4; ks++){
    bf16x8 av[2], bv[4];
    #pragma unroll
    for (int mi = 0; mi < 2; mi++){
      int l_ = w * 32 + mi * 16 + (lane & 15);
      av[mi] = *(const bf16x8*)(Cm + (size_t)(c * CL + l_) * 1024 + g * NS + ks * 32 + ((lane >> 4) << 3));
    }
    #pragma unroll
    for (int nj = 0; nj < 4; nj++){
      int p_ = nj * 16 + (lane & 15);
      bv[nj] = *(const bf16x8*)(Pp + (size_t)p_ * NS + ks * 32 + ((lane >> 4) << 3));
    }
    #pragma unroll
    for (int mi = 0; mi < 2; mi++)
      #pragma unroll
      for (int nj = 0; nj < 4; nj++)
        acc[mi][nj] = __builtin_amdgcn_mfma_f32_16x16x32_bf16(av[mi], bv[nj], acc[mi][nj], 0, 0, 0);
  }
  float dph = Dp[h];
  #pragma unroll
  for (int mi = 0; mi < 2; mi++)
  #pragma unroll
  for (int nj = 0; nj < 4; nj++)
  #pragma unroll
  for (int r = 0; r < 4; r++){
    int l_ = w * 32 + mi * 16 + ((lane >> 4) << 2) + r;
    int p_ = nj * 16 + (lane & 15);
    float e = expf(acs[((size_t)c * NH + h) * CL + l_]);
    size_t ix = (size_t)(c * CL + l_) * DI + h * 64 + p_;
    Y[ix] = Y[ix] + acc[mi][nj][r] * e + dph * bf2f(hid[ix]);
  }
}

// ---------------- 13. gate + group RMSNorm -> bf16 ----------------
__global__ __launch_bounds__(128) void k_gnorm(const float* __restrict__ Y, const u16* __restrict__ proj,
    const float* __restrict__ gw, u16* __restrict__ yn){
  int s = blockIdx.x; int g = blockIdx.y; int t = threadIdx.x;
  int col0 = g * 1024 + t * 8;
  const float* yp = Y + (size_t)s * DI + col0;
  float4 y0 = ((const float4*)yp)[0], y1 = ((const float4*)yp)[1];
  const u16* gp = proj + (size_t)s * PD + col0;
  float yg[8]; float ss = 0.f;
  #pragma unroll
  for (int i = 0; i < 8; i++){
    float yv = (i < 4) ? ((const float*)&y0)[i] : ((const float*)&y1)[i - 4];
    float gv = bf2f(gp[i]);
    yg[i] = yv * siluf(gv);
    ss += yg[i] * yg[i];
  }
  #pragma unroll
  for (int o = 32; o > 0; o >>= 1) ss += __shfl_down(ss, o);
  __shared__ float sr[2];
  if ((t & 63) == 0) sr[t >> 6] = ss;
  __syncthreads();
  float sc = rsqrtf((sr[0] + sr[1]) / 1024.f + EPSF);
  #pragma unroll
  for (int i = 0; i < 8; i++) yn[(size_t)s * DI + col0 + i] = f2bf(yg[i] * sc * gw[col0 + i]);
}

// ---------------- host ----------------
extern "C" void kernel_launch(void* const* d_in, const int* in_sizes, int n_in,
                              void* d_out, int out_size, void* d_ws, size_t ws_size,
                              hipStream_t stream){
  const float* x         = (const float*)d_in[0];
  const float* norm_w    = (const float*)d_in[1];
  const float* in_proj_w = (const float*)d_in[2];
  const float* conv_w    = (const float*)d_in[3];
  const float* conv_b    = (const float*)d_in[4];
  const float* dt_bias   = (const float*)d_in[5];
  const float* A_log     = (const float*)d_in[6];
  const float* Dp        = (const float*)d_in[7];
  const float* gnorm_w   = (const float*)d_in[8];
  const float* out_proj_w= (const float*)d_in[9];
  float* out = (float*)d_out;
  char* ws = (char*)d_ws;

  u16*   h     = (u16*)(ws + 0);                 // 16 MB
  u16*   w1    = (u16*)(ws + 16777216);          // 152 MB (reused by states+Y after gemm1)
  u16*   w2    = (u16*)(ws + 168820736);         // 67 MB (Mh lives here before cvt W2)
  u16*   mh    = w2;
  u16*   proj  = (u16*)(ws + 235929600);         // 76 MB
  float* dtraw = (float*)(ws + 311951360);       // 1 MB
  float* dtsp  = (float*)(ws + 312999936);       // 1 MB
  float* acs   = (float*)(ws + 314048512);       // 1 MB
  float* dec   = (float*)(ws + 315097088);       // 1 MB
  u16*   hid   = (u16*)(ws + 316145664);         // 33.5 MB
  u16*   hdtT  = (u16*)(ws + 349700096);         // 33.5 MB
  u16*   hddec = (u16*)(ws + 383254528);         // 33.5 MB
  u16*   Bm    = (u16*)(ws + 416808960);         // 4 MB
  u16*   Cm    = (u16*)(ws + 421003264);         // 4 MB
  u16*   BmT   = (u16*)(ws + 425197568);         // 4 MB
  u16*   prev  = (u16*)(ws + 429391872);         // 33.5 MB
  u16*   yn    = (u16*)(ws + 462946304);         // 33.5 MB  (end ~497 MB)
  float* states= (float*)(ws + 16777216);              // alias of w1 (dead after gemm1)
  float* Y     = (float*)(ws + 16777216 + 67108864);   // alias of w1 + 67MB

  k_rms<<<2048, 256, 0, stream>>>(x, norm_w, h);
  k_cvt<<<74240, 256, 0, stream>>>((const float4*)in_proj_w, (ushort4*)w1, 19005440);
  k_gemm_bt<0><<<dim3(145, 16), 256, 0, stream>>>(h, w1, proj, nullptr, dtraw, S_LEN, PD, DM);
  k_dt<<<1024, 256, 0, stream>>>(dtraw, dt_bias, dtsp);
  k_cumsum<<<16, 128, 0, stream>>>(dtsp, A_log, acs, dec);
  k_conv<<<81920, 256, 0, stream>>>(proj, conv_w, conv_b, hid, Bm, Cm);
  k_transpose<1><<<dim3(32, 128), 256, 0, stream>>>(hid, hdtT, hddec, dtsp, dec, S_LEN, DI);
  k_transpose<0><<<dim3(32, 16), 256, 0, stream>>>(Bm, BmT, nullptr, nullptr, nullptr, S_LEN, 1024);
  k_mh<<<dim3(16, 8), 256, 0, stream>>>(Cm, Bm, acs, mh);
  k_ydiag<<<2048, 256, 0, stream>>>(mh, hdtT, Y);
  k_cvt<<<32768, 256, 0, stream>>>((const float4*)out_proj_w, (ushort4*)w2, 8388608);
  k_states<<<2048, 256, 0, stream>>>(hddec, BmT, states);
  k_scan<<<4096, 256, 0, stream>>>(states, acs, prev);
  k_yoff<<<2048, 256, 0, stream>>>(Cm, prev, acs, Dp, hid, Y);
  k_gnorm<<<dim3(2048, 8), 128, 0, stream>>>(Y, proj, gnorm_w, yn);
  k_gemm_bt<1><<<dim3(32, 16), 256, 0, stream>>>(yn, w2, out, x, nullptr, S_LEN, DM, DI);
}